// Round 5
// baseline (269.997 us; speedup 1.0000x reference)
//
#include <hip/hip_runtime.h>

typedef __bf16 bf16;
typedef __bf16 bf16x4 __attribute__((ext_vector_type(4)));
typedef __bf16 bf16x8 __attribute__((ext_vector_type(8)));
typedef float  f32x4  __attribute__((ext_vector_type(4)));

#define TOKENS 16384
#define D_IN   4096
#define D_OUT  4096
#define RANK   512

// Async global->LDS, 16B per lane. LDS dest must be wave-uniform base + lane*16.
__device__ inline void gload_lds16(const bf16* g, bf16* l) {
    __builtin_amdgcn_global_load_lds((const __attribute__((address_space(1))) void*)g,
                                     (__attribute__((address_space(3))) void*)l,
                                     16, 0, 0);
}

// ---------------------------------------------------------------------------
// Prep 1: Vst[r][k'] = bf16(V[k][r] * sigma[r]), PRE-SWIZZLED (verified r3/r4:
//   conflicts -> 0). Within each 64-k block: k -> k ^ ((r&7)<<3).
// ---------------------------------------------------------------------------
__global__ __launch_bounds__(256) void vt_scale(const float* __restrict__ V,
                                                const float* __restrict__ sg,
                                                bf16* __restrict__ Vst) {
    __shared__ float tile[64][65];
    const int tx = threadIdx.x & 63;
    const int ty = threadIdx.x >> 6;
    const int kb = blockIdx.x * 64;
    const int rb = blockIdx.y * 64;
    const float s = sg[rb + tx];
#pragma unroll
    for (int i = ty; i < 64; i += 4)
        tile[i][tx] = V[(size_t)(kb + i) * RANK + rb + tx] * s;
    __syncthreads();
#pragma unroll
    for (int i = ty; i < 64; i += 4) {
        int r = rb + i;
        int kp = kb + (tx ^ ((r & 7) << 3));
        Vst[(size_t)r * D_IN + kp] = (bf16)tile[tx][i];
    }
}

// ---------------------------------------------------------------------------
// Prep 2: elementwise f32 -> bf16
// ---------------------------------------------------------------------------
__global__ __launch_bounds__(256) void cvt_bf16_4(const float* __restrict__ in,
                                                  bf16* __restrict__ o, int n4) {
    int i = blockIdx.x * 256 + threadIdx.x;
    if (i < n4) {
        f32x4 v = *(const f32x4*)(in + (size_t)i * 4);
        bf16x4 b = { (bf16)v[0], (bf16)v[1], (bf16)v[2], (bf16)v[3] };
        *(bf16x4*)(o + (size_t)i * 4) = b;
    }
}

// ---------------------------------------------------------------------------
// GEMM1 (T3+T4 counted pipeline): T = bf16( A_f32 @ B_bf16^T ), B pre-swizzled.
//   128x128, BK=64, 4 waves. A: 2-buf LDS, loads for tile i+1 issued at top of
//   iter i (latency hides under MFMA), cvt+ds_write after MFMA. B: 3-buf LDS,
//   gload_lds issued 2 tiles ahead -> steady-state wait is vmcnt(4), NEVER 0.
//   Raw s_barrier + lgkmcnt(0) only per step. LDS 80KB -> 2 blocks/CU.
// ---------------------------------------------------------------------------
__global__ __launch_bounds__(256) void gemm1_cnt(const float* __restrict__ A,
                                                 const bf16* __restrict__ B,
                                                 bf16* __restrict__ T,
                                                 int M, int N, int K) {
    __shared__ bf16 Al[2][128 * 64];   // 32 KB
    __shared__ bf16 Bl[3][128 * 64];   // 48 KB

    const int t  = threadIdx.x;
    const int l  = t & 63;
    const int w  = t >> 6;
    const int wr = w >> 1, wc = w & 1;
    const int lr = l & 15;
    const int kg = l >> 4;
    const int sxor = (lr & 7) << 3;

    // XCD-aware bijective swizzle (nwg=512, %8==0)
    const int nwg = gridDim.x;
    const int bid = blockIdx.x;
    const int cpx = nwg >> 3;
    const int swz = (bid & 7) * cpx + (bid >> 3);
    const int ntn = N >> 7;
    const int tm  = (swz / ntn) << 7;
    const int tn  = (swz % ntn) << 7;

    const int arow  = t >> 4;
    const int acg   = t & 15;
    const int awxor = (arow & 7) << 3;
    const float* Ap = A + (size_t)(tm + arow) * K + acg * 4;
    const bf16* Bp  = B + (size_t)(tn + (t >> 3)) * K + (t & 7) * 8;

    const int NT = K >> 6;   // 64 K-tiles

    f32x4 acc[4][4] = {};
    f32x4 ra[8];

    // ---- prologue: A[0] loads, B[0] + B[1] DMA, write A[0] ----
#pragma unroll
    for (int c = 0; c < 8; ++c)
        ra[c] = *(const f32x4*)(Ap + (size_t)(c * 16) * K);
#pragma unroll
    for (int c = 0; c < 4; ++c)
        gload_lds16(Bp + (size_t)(c * 32) * K, &Bl[0][(c * 256 + t) * 8]);
#pragma unroll
    for (int c = 0; c < 4; ++c)
        gload_lds16(Bp + 64 + (size_t)(c * 32) * K, &Bl[1][(c * 256 + t) * 8]);
#pragma unroll
    for (int c = 0; c < 8; ++c) {
        bf16x4 b = { (bf16)ra[c][0], (bf16)ra[c][1], (bf16)ra[c][2], (bf16)ra[c][3] };
        *(bf16x4*)&Al[0][(c * 16 + arow) * 64 + ((acg * 4) ^ awxor)] = b;
    }
    // B[0] done (B[1] stays in flight), ds_writes drained
    asm volatile("s_waitcnt vmcnt(4) lgkmcnt(0)" ::: "memory");
    __builtin_amdgcn_sched_barrier(0);
    __builtin_amdgcn_s_barrier();
    __builtin_amdgcn_sched_barrier(0);

    int bb = 0;   // B buffer of current tile (= i % 3)
    for (int i = 0; i < NT; ++i) {
        const int kt = i << 6;
        const bf16* Alc = &Al[i & 1][0];
        const bf16* Blc = &Bl[bb][0];
        const int bb2 = (bb >= 1) ? bb - 1 : 2;   // (bb+2)%3

        // ---- issue next-tile A loads (oldest in vmcnt FIFO this iter) ----
        if (i + 1 < NT) {
#pragma unroll
            for (int c = 0; c < 8; ++c)
                ra[c] = *(const f32x4*)(Ap + kt + 64 + (size_t)(c * 16) * K);
        }
        // ---- issue B DMA two tiles ahead ----
        if (i + 2 < NT) {
#pragma unroll
            for (int c = 0; c < 4; ++c)
                gload_lds16(Bp + kt + 128 + (size_t)(c * 32) * K,
                            &Bl[bb2][(c * 256 + t) * 8]);
        }

        // ---- compute tile i ----
#pragma unroll
        for (int ks = 0; ks < 2; ++ks) {
            bf16x8 af[4], bfr[4];
#pragma unroll
            for (int f = 0; f < 4; ++f) {
                af[f]  = *(const bf16x8*)&Alc[(wr * 64 + f * 16 + lr) * 64 + ((ks * 32 + kg * 8) ^ sxor)];
                bfr[f] = *(const bf16x8*)&Blc[(wc * 64 + f * 16 + lr) * 64 + ((ks * 32 + kg * 8) ^ sxor)];
            }
#pragma unroll
            for (int fm = 0; fm < 4; ++fm)
#pragma unroll
                for (int fn = 0; fn < 4; ++fn)
                    acc[fm][fn] = __builtin_amdgcn_mfma_f32_16x16x32_bf16(
                        af[fm], bfr[fn], acc[fm][fn], 0, 0, 0);
        }

        if (i + 1 < NT) {
            // cvt + ds_write A[i+1] (compiler's dataflow wait for ra = vmcnt(4))
#pragma unroll
            for (int c = 0; c < 8; ++c) {
                bf16x4 b = { (bf16)ra[c][0], (bf16)ra[c][1], (bf16)ra[c][2], (bf16)ra[c][3] };
                *(bf16x4*)&Al[(i + 1) & 1][(c * 16 + arow) * 64 + ((acg * 4) ^ awxor)] = b;
            }
            // steady state: leave B[i+2]'s 4 DMAs in flight; tail: drain
            if (i + 2 < NT)
                asm volatile("s_waitcnt vmcnt(4) lgkmcnt(0)" ::: "memory");
            else
                asm volatile("s_waitcnt vmcnt(0) lgkmcnt(0)" ::: "memory");
            __builtin_amdgcn_sched_barrier(0);
            __builtin_amdgcn_s_barrier();
            __builtin_amdgcn_sched_barrier(0);
        }
        bb = (bb + 1 == 3) ? 0 : bb + 1;
    }

    // ---- C-write: col = lane&15, row = (lane>>4)*4 + reg ----
    const int r0 = tm + wr * 64 + kg * 4;
    const int c0 = tn + wc * 64 + lr;
#pragma unroll
    for (int fm = 0; fm < 4; ++fm)
#pragma unroll
        for (int fn = 0; fn < 4; ++fn)
#pragma unroll
            for (int r = 0; r < 4; ++r)
                T[(size_t)(r0 + fm * 16 + r) * N + (c0 + fn * 16)] = (bf16)acc[fm][fn][r];
}

// ---------------------------------------------------------------------------
// GEMM2 (issue-early 2-phase): C_f32 = A_bf16 @ B_bf16^T. Stage[i+1] DMA is
//   issued BEFORE computing tile i, so the vmcnt(0) at the step end is nearly
//   free (DMA flew under 128 MFMAs). 2-buf LDS 64KB -> 2 blocks/CU.
// ---------------------------------------------------------------------------
__global__ __launch_bounds__(256) void gemm2_pf(const bf16* __restrict__ A,
                                                const bf16* __restrict__ B,
                                                float* __restrict__ out,
                                                int M, int N, int K) {
    __shared__ bf16 Al[2][128 * 64];
    __shared__ bf16 Bl[2][128 * 64];

    const int t  = threadIdx.x;
    const int l  = t & 63;
    const int w  = t >> 6;
    const int wr = w >> 1, wc = w & 1;
    const int lr = l & 15;
    const int kg = l >> 4;

    const int nwg = gridDim.x;
    const int bid = blockIdx.x;
    const int cpx = nwg >> 3;
    const int swz = (bid & 7) * cpx + (bid >> 3);
    const int ntn = N >> 7;
    const int tm  = (swz / ntn) << 7;
    const int tn  = (swz % ntn) << 7;

    const bf16* Apt = A + (size_t)(tm + (t >> 3)) * K + (t & 7) * 8;
    const bf16* Bpt = B + (size_t)(tn + (t >> 3)) * K + (t & 7) * 8;

    const int NT = K >> 6;   // 8 K-tiles

    f32x4 acc[4][4] = {};

    // ---- prologue: stage tile 0 ----
#pragma unroll
    for (int c = 0; c < 4; ++c) {
        gload_lds16(Apt + (size_t)(c * 32) * K, &Al[0][(c * 256 + t) * 8]);
        gload_lds16(Bpt + (size_t)(c * 32) * K, &Bl[0][(c * 256 + t) * 8]);
    }
    asm volatile("s_waitcnt vmcnt(0)" ::: "memory");
    __builtin_amdgcn_sched_barrier(0);
    __builtin_amdgcn_s_barrier();
    __builtin_amdgcn_sched_barrier(0);

    for (int i = 0; i < NT; ++i) {
        const int kt = i << 6;
        // ---- issue next tile's DMA first ----
        if (i + 1 < NT) {
#pragma unroll
            for (int c = 0; c < 4; ++c) {
                gload_lds16(Apt + kt + 64 + (size_t)(c * 32) * K, &Al[(i + 1) & 1][(c * 256 + t) * 8]);
                gload_lds16(Bpt + kt + 64 + (size_t)(c * 32) * K, &Bl[(i + 1) & 1][(c * 256 + t) * 8]);
            }
        }
        // ---- compute tile i ----
#pragma unroll
        for (int ks = 0; ks < 2; ++ks) {
            bf16x8 af[4], bfr[4];
#pragma unroll
            for (int f = 0; f < 4; ++f) {
                af[f]  = *(const bf16x8*)&Al[i & 1][(wr * 64 + f * 16 + lr) * 64 + ks * 32 + kg * 8];
                bfr[f] = *(const bf16x8*)&Bl[i & 1][(wc * 64 + f * 16 + lr) * 64 + ks * 32 + kg * 8];
            }
#pragma unroll
            for (int fm = 0; fm < 4; ++fm)
#pragma unroll
                for (int fn = 0; fn < 4; ++fn)
                    acc[fm][fn] = __builtin_amdgcn_mfma_f32_16x16x32_bf16(
                        af[fm], bfr[fn], acc[fm][fn], 0, 0, 0);
        }
        if (i + 1 < NT) {
            asm volatile("s_waitcnt vmcnt(0)" ::: "memory");
            __builtin_amdgcn_sched_barrier(0);
            __builtin_amdgcn_s_barrier();
            __builtin_amdgcn_sched_barrier(0);
        }
    }

    const int r0 = tm + wr * 64 + kg * 4;
    const int c0 = tn + wc * 64 + lr;
#pragma unroll
    for (int fm = 0; fm < 4; ++fm)
#pragma unroll
        for (int fn = 0; fn < 4; ++fn)
#pragma unroll
            for (int r = 0; r < 4; ++r)
                out[(size_t)(r0 + fm * 16 + r) * N + (c0 + fn * 16)] = acc[fm][fn][r];
}

// ---------------------------------------------------------------------------
extern "C" void kernel_launch(void* const* d_in, const int* in_sizes, int n_in,
                              void* d_out, int out_size, void* d_ws, size_t ws_size,
                              hipStream_t stream) {
    const float* x  = (const float*)d_in[0];  // [16384][4096]
    const float* U  = (const float*)d_in[1];  // [4096][512]
    const float* sg = (const float*)d_in[2];  // [512]
    const float* V  = (const float*)d_in[3];  // [4096][512]
    float* out = (float*)d_out;               // [16384][4096] f32

    char* ws = (char*)d_ws;
    bf16* Vst = (bf16*)ws;                    // [512][4096]  = 4 MB (pre-swizzled)
    bf16* Ub  = (bf16*)(ws + (4u << 20));     // [4096][512]  = 4 MB
    bf16* T   = (bf16*)(ws + (8u << 20));     // [16384][512] = 16 MB

    vt_scale<<<dim3(D_IN / 64, RANK / 64), 256, 0, stream>>>(V, sg, Vst);
    cvt_bf16_4<<<(D_OUT * RANK / 4 + 255) / 256, 256, 0, stream>>>(U, Ub, D_OUT * RANK / 4);

    // GEMM1: T = bf16( x @ Vst^T ), grid 128*4 = 512 blocks
    gemm1_cnt<<<(TOKENS / 128) * (RANK / 128), 256, 0, stream>>>(
        x, Vst, T, TOKENS, RANK, D_IN);

    // GEMM2: out = T @ Ub^T (f32 out), grid 128*32 = 4096 blocks
    gemm2_pf<<<(TOKENS / 128) * (D_OUT / 128), 256, 0, stream>>>(
        T, Ub, out, TOKENS, D_OUT, RANK);
}